// Round 5
// baseline (157.418 us; speedup 1.0000x reference)
//
#include <hip/hip_runtime.h>
#include <cstdint>

// ---------------- problem constants ----------------
#define DD     256
#define HH     1024
#define NNSEQ  4096
#define MT     64            // tokens per block (grid 256, 1024 thr)
#define XR     78            // MT + 14 halo rows
#define XPITCH 264           // 256 + 8 pad (bf16 elems), row 528 B
#define SLOTP  260           // fp32 slot pitch
#define EPSLN  1e-5f

typedef unsigned short u16;
typedef __attribute__((ext_vector_type(8))) short short8;
typedef __attribute__((ext_vector_type(4))) float f32x4;

#define MFMA(a, b, c) __builtin_amdgcn_mfma_f32_16x16x32_bf16(a, b, c, 0, 0, 0)

__device__ __forceinline__ u16 f2bf(float f) {           // RNE fp32 -> bf16
  unsigned u = __float_as_uint(f);
  u += 0x7FFF + ((u >> 16) & 1);
  return (u16)(u >> 16);
}
__device__ __forceinline__ float bf2f(u16 s) { return __uint_as_float(((unsigned)s) << 16); }

// tanh-form GELU via sigmoid identity: 0.5v(1+tanh(u)) = v*sigmoid(2u).
// Max |err| vs exact erf-GELU ~3e-4, under the bf16 quantization applied after.
__device__ __forceinline__ float fast_gelu(float v) {
  const float e = __expf(v * __builtin_fmaf(v * v, -0.0713548163f, -1.5957691216f));
  return v * __builtin_amdgcn_rcpf(1.f + e);
}

// ======== prep: pack weights into MFMA B-fragment slabs (unchanged) ========
// slab: 32 K-rows x 256 N-cols fp32 -> 8192 bf16:
//   dst[fi*512 + l*8 + j] = W[k = s*32 + (l>>4)*8 + j][n = fi*16 + (l&15)]
__global__ __launch_bounds__(256) void k_prep(
    const float* __restrict__ wmix, const float* __restrict__ wff1,
    const float* __restrict__ wff2, u16* __restrict__ wpk,
    u16* __restrict__ w1pk, u16* __restrict__ w2pk)
{
  __shared__ float t[32][257];
  const int b = blockIdx.x, tid = threadIdx.x;

  u16* dst;
  if (b < 120) {                                   // conv: slab s = b
    dst = wpk + (size_t)b * 8192;
    for (int r = 0; r < 32; ++r)
      t[r][tid] = wmix[(size_t)(b * 32 + r) * 256 + tid];
  } else if (b < 152) {                            // FF1: u = c2*8+s
    const int u = b - 120, c2 = u >> 3, s = u & 7;
    dst = w1pk + (size_t)u * 8192;
    for (int r = 0; r < 32; ++r)
      t[r][tid] = wff1[(size_t)(s * 32 + r) * 1024 + c2 * 256 + tid];
  } else {                                         // FF2: u = c2*8+s
    const int u = b - 152, c2 = u >> 3, s = u & 7;
    dst = w2pk + (size_t)u * 8192;
    for (int r = 0; r < 32; ++r)
      t[r][tid] = wff2[(size_t)(c2 * 256 + s * 32 + r) * 256 + tid];
  }
  __syncthreads();

  const int l = tid & 63, q = l >> 4, cl = l & 15;
#pragma unroll
  for (int f = 0; f < 4; ++f) {
    const int fi = f * 4 + (tid >> 6);
    const int n = fi * 16 + cl;
    uint4 pk;
    unsigned* p = (unsigned*)&pk;
#pragma unroll
    for (int jj = 0; jj < 4; ++jj)
      p[jj] = (unsigned)f2bf(t[q * 8 + jj * 2][n]) | ((unsigned)f2bf(t[q * 8 + jj * 2 + 1][n]) << 16);
    *(uint4*)&dst[(size_t)fi * 512 + l * 8] = pk;
  }
}

// ===== fused MT=64: 16 waves = 2 mg (K-half) x 4 ng (64 cols) x 2 rg ====
// R5: same per-wave tile as R4 (32 rows x 64 cols x K=1920), doubled rows
// per block.  rg-pair waves read IDENTICAL B addresses -> L1 dedups the
// second stream, halving unique L2 weight traffic per token (the dominant
// cost, ~44 us of 76.6).  16 waves/CU = 4/SIMD preserved; LDS ~113 KB,
// grid 256 = 1 block/CU exactly.
__global__ __launch_bounds__(1024, 4) void k_fused(
    const float* __restrict__ x, const u16* __restrict__ wpk,
    const float* __restrict__ bmix, const float* __restrict__ g1,
    const float* __restrict__ b1, const u16* __restrict__ w1pk,
    const float* __restrict__ bf1, const u16* __restrict__ w2pk,
    const float* __restrict__ bf2, const float* __restrict__ g2,
    const float* __restrict__ b2, float* __restrict__ out)
{
  __shared__ __align__(16) u16 bufA[XR * XPITCH];      // 41.2 KB: xs, then h rows 0..63
  __shared__ __align__(16) u16 asbuf[2 * MT * XPITCH]; // 67.6 KB: fp32 slot / 2x gelu buf
  __shared__ float redS[8][MT], redS2[8][MT];          // 4 KB
  __shared__ float muL[MT], invL[MT];                  // 0.5 KB

#define bufB ((float*)asbuf)                       // [MT][SLOTP] conv combine slot

  const int tid = threadIdx.x;
  const int wv = tid >> 6, l = tid & 63, q = l >> 4, cl = l & 15;
  const int rg = wv >> 3;                          // row half (rows rg*32..)
  const int mgq = (wv >> 2) & 1;                   // conv K-half
  const int ng = wv & 3;                           // conv col group (64 cols)
  const int cg = wv & 7;                           // FFN col group (32 cols)
  const long tok0 = (long)blockIdx.x * MT;
  const int n0 = (int)(tok0 & (NNSEQ - 1));

  // ---- acc init + base pointers hoisted above staging ----
  f32x4 acc[2][4];
#pragma unroll
  for (int nt = 0; nt < 4; ++nt) {
    const float bm = (mgq == 0) ? bmix[ng * 64 + nt * 16 + cl] : 0.f;
#pragma unroll
    for (int mt = 0; mt < 2; ++mt) acc[mt][nt] = (f32x4){bm, bm, bm, bm};
  }
  const u16* bbase = wpk + (size_t)(mgq * 60) * 8192 + (size_t)(ng * 4) * 512 + (size_t)l * 8;

  // ---- stage x rows [tok0-14, tok0+63] as bf16 ----
  {
    const int cslot = l * 4;
    for (int r = wv; r < XR; r += 16) {
      const int nloc = n0 - 14 + r;
      float4 v = make_float4(0.f, 0.f, 0.f, 0.f);
      if (nloc >= 0) v = *(const float4*)&x[(tok0 - 14 + r) * DD + cslot];
      uint2 pk;
      pk.x = (unsigned)f2bf(v.x) | ((unsigned)f2bf(v.y) << 16);
      pk.y = (unsigned)f2bf(v.z) | ((unsigned)f2bf(v.w) << 16);
      *(uint2*)&bufA[r * XPITCH + cslot] = pk;
    }
  }

#define LOAD_A(dst, s_)                                                         \
  {                                                                             \
    const int ks = mgq * 60 + (s_);                                             \
    const int xrow = ks >> 3, c0 = (ks & 7) * 32;                               \
    _Pragma("unroll")                                                           \
    for (int mt = 0; mt < 2; ++mt)                                              \
      dst[mt] = *(const short8*)&bufA[(xrow + rg * 32 + mt * 16 + cl) * XPITCH + c0 + q * 8]; \
  }
#define LOAD_B(dst, s_)                                                         \
  {                                                                             \
    const u16* bp = bbase + (size_t)(s_) * 8192;                                \
    _Pragma("unroll")                                                           \
    for (int nt = 0; nt < 4; ++nt)                                              \
      dst[nt] = *(const short8*)(bp + nt * 512);                                \
  }

  // ====== conv GEMM: K-half mgq, cols ng*64.., rows rg*32.. (32x64) =====
  // Depth-3 pipeline; B (global) for steps 0..2 issued BEFORE the barrier.
  {
    short8 af[3][2], bfr[3][4];
    LOAD_B(bfr[0], 0)
    LOAD_B(bfr[1], 1)
    LOAD_B(bfr[2], 2)
    __syncthreads();
    LOAD_A(af[0], 0)
    LOAD_A(af[1], 1)
    LOAD_A(af[2], 2)

    for (int sb = 0; sb < 57; sb += 3) {
#pragma unroll
      for (int u = 0; u < 3; ++u) {
#pragma unroll
        for (int mt = 0; mt < 2; ++mt)
#pragma unroll
          for (int nt = 0; nt < 4; ++nt)
            acc[mt][nt] = MFMA(af[u][mt], bfr[u][nt], acc[mt][nt]);
        LOAD_A(af[u], sb + u + 3)
        LOAD_B(bfr[u], sb + u + 3)
      }
    }
#pragma unroll
    for (int u = 0; u < 3; ++u) {                  // tail: steps 57..59
#pragma unroll
      for (int mt = 0; mt < 2; ++mt)
#pragma unroll
        for (int nt = 0; nt < 4; ++nt)
          acc[mt][nt] = MFMA(af[u][mt], bfr[u][nt], acc[mt][nt]);
    }
  }
#undef LOAD_A
#undef LOAD_B

  // ---- mg1 -> fp32 slot; mg0 combines + residual + LN1 ----
  if (mgq == 1) {
#pragma unroll
    for (int mt = 0; mt < 2; ++mt)
#pragma unroll
      for (int nt = 0; nt < 4; ++nt)
#pragma unroll
        for (int reg = 0; reg < 4; ++reg)
          bufB[(rg * 32 + mt * 16 + q * 4 + reg) * SLOTP + ng * 64 + nt * 16 + cl] = acc[mt][nt][reg];
  }
  __syncthreads();

  if (mgq == 0) {
    float ps[2][4], ps2[2][4];
#pragma unroll
    for (int mt = 0; mt < 2; ++mt)
#pragma unroll
      for (int reg = 0; reg < 4; ++reg) {
        const int row = rg * 32 + mt * 16 + q * 4 + reg;
        float s = 0.f, s2 = 0.f;
#pragma unroll
        for (int nt = 0; nt < 4; ++nt) {
          const int col = ng * 64 + nt * 16 + cl;
          const float y = acc[mt][nt][reg] + bufB[row * SLOTP + col]
                        + x[(tok0 + row) * DD + col];        // fp32 residual
          acc[mt][nt][reg] = y;
          s += y; s2 += y * y;
        }
#pragma unroll
        for (int off = 1; off < 16; off <<= 1) { s += __shfl_xor(s, off, 64); s2 += __shfl_xor(s2, off, 64); }
        ps[mt][reg] = s; ps2[mt][reg] = s2;
      }
    if (cl == 0) {
#pragma unroll
      for (int mt = 0; mt < 2; ++mt)
#pragma unroll
        for (int reg = 0; reg < 4; ++reg) {
          const int row = rg * 32 + mt * 16 + q * 4 + reg;
          redS[ng][row] = ps[mt][reg]; redS2[ng][row] = ps2[mt][reg];
        }
    }
  }
  __syncthreads();
  if (tid < MT) {
    const float s  = redS[0][tid] + redS[1][tid] + redS[2][tid] + redS[3][tid];
    const float s2 = redS2[0][tid] + redS2[1][tid] + redS2[2][tid] + redS2[3][tid];
    const float mu = s * (1.f / DD);
    const float var = s2 * (1.f / DD) - mu * mu;
    muL[tid] = mu; invL[tid] = rsqrtf(var + EPSLN);
  }
  __syncthreads();

  // ---- h (bf16) -> bufA rows 0..63 ----
  if (mgq == 0) {
#pragma unroll
    for (int nt = 0; nt < 4; ++nt) {
      const int col = ng * 64 + nt * 16 + cl;
      const float gv = g1[col], bv = b1[col];
#pragma unroll
      for (int mt = 0; mt < 2; ++mt)
#pragma unroll
        for (int reg = 0; reg < 4; ++reg) {
          const int row = rg * 32 + mt * 16 + q * 4 + reg;
          const float hv = (acc[mt][nt][reg] - muL[row]) * invL[row] * gv + bv;
          bufA[row * XPITCH + col] = f2bf(hv);
        }
    }
  }
  __syncthreads();

  // ============ FFN: 4 chunks of 256 H-cols; wave tile 32 x 32 ============
  // wave (rg, cg): rows rg*32.., cols cg*32.. of the chunk.  rg-pairs read
  // identical B addresses (L1 dedup).  asb double-buffered by chunk parity.
  f32x4 acc2[2][2];
#pragma unroll
  for (int nt = 0; nt < 2; ++nt) {
    const float bv = bf2[cg * 32 + nt * 16 + cl];
#pragma unroll
    for (int mt = 0; mt < 2; ++mt) acc2[mt][nt] = (f32x4){bv, bv, bv, bv};
  }

#define FF_LDA(src, dst, s_)                                                    \
  {                                                                             \
    _Pragma("unroll")                                                           \
    for (int mt = 0; mt < 2; ++mt)                                              \
      dst[mt] = *(const short8*)&src[(rg * 32 + mt * 16 + cl) * XPITCH + (s_) * 32 + q * 8]; \
  }
#define FF_LDB(wsrc, dst, s_)                                                   \
  {                                                                             \
    const u16* bp = wsrc + (size_t)(c * 8 + (s_)) * 8192 + (size_t)(cg * 2) * 512 + (size_t)l * 8; \
    _Pragma("unroll")                                                           \
    for (int nt = 0; nt < 2; ++nt)                                              \
      dst[nt] = *(const short8*)(bp + nt * 512);                                \
  }

  for (int c = 0; c < 4; ++c) {
    u16* asb = asbuf + (c & 1) * (MT * XPITCH);
    // FF1: rows rg*32.. x chunk-cols [cg*32,+32), K = 256
    f32x4 acc1[2][2];
#pragma unroll
    for (int nt = 0; nt < 2; ++nt) {
      const float bv = bf1[c * 256 + cg * 32 + nt * 16 + cl];
#pragma unroll
      for (int mt = 0; mt < 2; ++mt) acc1[mt][nt] = (f32x4){bv, bv, bv, bv};
    }
    {
      short8 a2[2][2], b2r[2][2];
      FF_LDA(bufA, a2[0], 0) FF_LDB(w1pk, b2r[0], 0)
      FF_LDA(bufA, a2[1], 1) FF_LDB(w1pk, b2r[1], 1)
#pragma unroll
      for (int s = 0; s < 6; ++s) {
        const int cur = s & 1;
#pragma unroll
        for (int mt = 0; mt < 2; ++mt)
#pragma unroll
          for (int nt = 0; nt < 2; ++nt)
            acc1[mt][nt] = MFMA(a2[cur][mt], b2r[cur][nt], acc1[mt][nt]);
        FF_LDA(bufA, a2[cur], s + 2) FF_LDB(w1pk, b2r[cur], s + 2)
      }
#pragma unroll
      for (int s = 6; s < 8; ++s) {
        const int cur = s & 1;
#pragma unroll
        for (int mt = 0; mt < 2; ++mt)
#pragma unroll
          for (int nt = 0; nt < 2; ++nt)
            acc1[mt][nt] = MFMA(a2[cur][mt], b2r[cur][nt], acc1[mt][nt]);
      }
    }
    // fast gelu -> asb (A-layout, chunk-local cols cg*32+nt*16+cl)
#pragma unroll
    for (int mt = 0; mt < 2; ++mt)
#pragma unroll
      for (int nt = 0; nt < 2; ++nt)
#pragma unroll
        for (int reg = 0; reg < 4; ++reg) {
          const float g = fast_gelu(acc1[mt][nt][reg]);
          asb[(rg * 32 + mt * 16 + q * 4 + reg) * XPITCH + cg * 32 + nt * 16 + cl] = f2bf(g);
        }
    __syncthreads();
    // FF2: rows rg*32.. x out-cols [cg*32,+32), K = chunk's 256
    {
      short8 a2[2][2], b2r[2][2];
      FF_LDA(asb, a2[0], 0) FF_LDB(w2pk, b2r[0], 0)
      FF_LDA(asb, a2[1], 1) FF_LDB(w2pk, b2r[1], 1)
#pragma unroll
      for (int s = 0; s < 6; ++s) {
        const int cur = s & 1;
#pragma unroll
        for (int mt = 0; mt < 2; ++mt)
#pragma unroll
          for (int nt = 0; nt < 2; ++nt)
            acc2[mt][nt] = MFMA(a2[cur][mt], b2r[cur][nt], acc2[mt][nt]);
        FF_LDA(asb, a2[cur], s + 2) FF_LDB(w2pk, b2r[cur], s + 2)
      }
#pragma unroll
      for (int s = 6; s < 8; ++s) {
        const int cur = s & 1;
#pragma unroll
        for (int mt = 0; mt < 2; ++mt)
#pragma unroll
          for (int nt = 0; nt < 2; ++nt)
            acc2[mt][nt] = MFMA(a2[cur][mt], b2r[cur][nt], acc2[mt][nt]);
      }
    }
    // no trailing barrier: next chunk writes the other asb buffer
  }
#undef FF_LDA
#undef FF_LDB

  // ---- residual (h from bufA) + LN2 ----
  {
    float ps[2][4], ps2[2][4];
#pragma unroll
    for (int mt = 0; mt < 2; ++mt)
#pragma unroll
      for (int reg = 0; reg < 4; ++reg) {
        const int row = rg * 32 + mt * 16 + q * 4 + reg;
        float s = 0.f, s2 = 0.f;
#pragma unroll
        for (int nt = 0; nt < 2; ++nt) {
          const int col = cg * 32 + nt * 16 + cl;
          const float y = acc2[mt][nt][reg] + bf2f(bufA[row * XPITCH + col]);
          acc2[mt][nt][reg] = y;
          s += y; s2 += y * y;
        }
#pragma unroll
        for (int off = 1; off < 16; off <<= 1) { s += __shfl_xor(s, off, 64); s2 += __shfl_xor(s2, off, 64); }
        ps[mt][reg] = s; ps2[mt][reg] = s2;
      }
    if (cl == 0) {
#pragma unroll
      for (int mt = 0; mt < 2; ++mt)
#pragma unroll
        for (int reg = 0; reg < 4; ++reg) {
          const int row = rg * 32 + mt * 16 + q * 4 + reg;
          redS[cg][row] = ps[mt][reg]; redS2[cg][row] = ps2[mt][reg];
        }
    }
  }
  __syncthreads();
  if (tid < MT) {
    float s = 0.f, s2 = 0.f;
#pragma unroll
    for (int k = 0; k < 8; ++k) { s += redS[k][tid]; s2 += redS2[k][tid]; }
    const float mu = s * (1.f / DD);
    const float var = s2 * (1.f / DD) - mu * mu;
    muL[tid] = mu; invL[tid] = rsqrtf(var + EPSLN);
  }
  __syncthreads();

#pragma unroll
  for (int nt = 0; nt < 2; ++nt) {
    const int col = cg * 32 + nt * 16 + cl;
    const float gv = g2[col], bv = b2[col];
#pragma unroll
    for (int mt = 0; mt < 2; ++mt)
#pragma unroll
      for (int reg = 0; reg < 4; ++reg) {
        const int row = rg * 32 + mt * 16 + q * 4 + reg;
        out[(tok0 + row) * DD + col] = (acc2[mt][nt][reg] - muL[row]) * invL[row] * gv + bv;
      }
  }
#undef bufB
}

// ---------------- launch ----------------
extern "C" void kernel_launch(void* const* d_in, const int* in_sizes, int n_in,
                              void* d_out, int out_size, void* d_ws, size_t ws_size,
                              hipStream_t stream) {
  const float* x    = (const float*)d_in[0];
  const float* wmix = (const float*)d_in[1];   // [3840][256]
  const float* bmix = (const float*)d_in[2];
  const float* g1   = (const float*)d_in[3];
  const float* b1   = (const float*)d_in[4];
  const float* wff1 = (const float*)d_in[5];   // [256][1024]
  const float* bff1 = (const float*)d_in[6];
  const float* wff2 = (const float*)d_in[7];   // [1024][256]
  const float* bff2 = (const float*)d_in[8];
  const float* g2   = (const float*)d_in[9];
  const float* b2   = (const float*)d_in[10];
  float* out = (float*)d_out;

  u16* wpk  = (u16*)d_ws;                // 120*8192 = 983040 elems (1.97 MB)
  u16* w1pk = wpk + 983040;              // 32*8192 = 262144
  u16* w2pk = w1pk + 262144;             // 262144

  k_prep<<<184, 256, 0, stream>>>(wmix, wff1, wff2, wpk, w1pk, w2pk);

  k_fused<<<256, 1024, 0, stream>>>(x, wpk, bmix, g1, b1,
                                    w1pk, bff1, w2pk, bff2, g2, b2, out);
}

// Round 6
// 149.762 us; speedup vs baseline: 1.0511x; 1.0511x over previous
//
#include <hip/hip_runtime.h>
#include <cstdint>

// ---------------- problem constants ----------------
#define DD     256
#define HH     1024
#define NNSEQ  4096
#define MT     64            // tokens per block (grid 256, 1024 thr)
#define XR     78            // MT + 14 halo rows
#define XPITCH 264           // 256 + 8 pad (bf16 elems), row 528 B
#define SLOTP  260           // fp32 slot pitch
#define EPSLN  1e-5f

typedef unsigned short u16;
typedef __attribute__((ext_vector_type(8))) short short8;
typedef __attribute__((ext_vector_type(4))) float f32x4;

#define MFMA(a, b, c) __builtin_amdgcn_mfma_f32_16x16x32_bf16(a, b, c, 0, 0, 0)

__device__ __forceinline__ u16 f2bf(float f) {           // RNE fp32 -> bf16
  unsigned u = __float_as_uint(f);
  u += 0x7FFF + ((u >> 16) & 1);
  return (u16)(u >> 16);
}
__device__ __forceinline__ float bf2f(u16 s) { return __uint_as_float(((unsigned)s) << 16); }

// tanh-form GELU via sigmoid identity: 0.5v(1+tanh(u)) = v*sigmoid(2u).
// Max |err| vs exact erf-GELU ~3e-4, under the bf16 quantization applied after.
__device__ __forceinline__ float fast_gelu(float v) {
  const float e = __expf(v * __builtin_fmaf(v * v, -0.0713548163f, -1.5957691216f));
  return v * __builtin_amdgcn_rcpf(1.f + e);
}

// ======== prep: pack weights into MFMA B-fragment slabs (unchanged) ========
// slab: 32 K-rows x 256 N-cols fp32 -> 8192 bf16:
//   dst[fi*512 + l*8 + j] = W[k = s*32 + (l>>4)*8 + j][n = fi*16 + (l&15)]
__global__ __launch_bounds__(256) void k_prep(
    const float* __restrict__ wmix, const float* __restrict__ wff1,
    const float* __restrict__ wff2, u16* __restrict__ wpk,
    u16* __restrict__ w1pk, u16* __restrict__ w2pk)
{
  __shared__ float t[32][257];
  const int b = blockIdx.x, tid = threadIdx.x;

  u16* dst;
  if (b < 120) {                                   // conv: slab s = b
    dst = wpk + (size_t)b * 8192;
    for (int r = 0; r < 32; ++r)
      t[r][tid] = wmix[(size_t)(b * 32 + r) * 256 + tid];
  } else if (b < 152) {                            // FF1: u = c2*8+s
    const int u = b - 120, c2 = u >> 3, s = u & 7;
    dst = w1pk + (size_t)u * 8192;
    for (int r = 0; r < 32; ++r)
      t[r][tid] = wff1[(size_t)(s * 32 + r) * 1024 + c2 * 256 + tid];
  } else {                                         // FF2: u = c2*8+s
    const int u = b - 152, c2 = u >> 3, s = u & 7;
    dst = w2pk + (size_t)u * 8192;
    for (int r = 0; r < 32; ++r)
      t[r][tid] = wff2[(size_t)(c2 * 256 + s * 32 + r) * 256 + tid];
  }
  __syncthreads();

  const int l = tid & 63, q = l >> 4, cl = l & 15;
#pragma unroll
  for (int f = 0; f < 4; ++f) {
    const int fi = f * 4 + (tid >> 6);
    const int n = fi * 16 + cl;
    uint4 pk;
    unsigned* p = (unsigned*)&pk;
#pragma unroll
    for (int jj = 0; jj < 4; ++jj)
      p[jj] = (unsigned)f2bf(t[q * 8 + jj * 2][n]) | ((unsigned)f2bf(t[q * 8 + jj * 2 + 1][n]) << 16);
    *(uint4*)&dst[(size_t)fi * 512 + l * 8] = pk;
  }
}

// ===== fused MT=64 =====
// R6: conv wave tile changed to TALL: 16 waves = 2 mg (K-half) x 8 ng
// (32 cols), each wave mt=4 (ALL 64 rows) x nt=2.  B-bytes per MFMA halve
// (512 -> 256 B): per-CU conv L2 demand drops from ~105 B/cy to ~53 B/cy
// ~= the 56 B/cy per-CU L2 share -- removes the 2x oversubscription that
// R5 failed to fix via L1 dedup.  No B duplication: 16 waves cover
// 64 x 256 x K exactly once.  FFN/LN/slot structure = R5 (verified).
__global__ __launch_bounds__(1024, 4) void k_fused(
    const float* __restrict__ x, const u16* __restrict__ wpk,
    const float* __restrict__ bmix, const float* __restrict__ g1,
    const float* __restrict__ b1, const u16* __restrict__ w1pk,
    const float* __restrict__ bf1, const u16* __restrict__ w2pk,
    const float* __restrict__ bf2, const float* __restrict__ g2,
    const float* __restrict__ b2, float* __restrict__ out)
{
  __shared__ __align__(16) u16 bufA[XR * XPITCH];      // 41.2 KB: xs, then h rows 0..63
  __shared__ __align__(16) u16 asbuf[2 * MT * XPITCH]; // 67.6 KB: fp32 slot / 2x gelu buf
  __shared__ float redS[8][MT], redS2[8][MT];          // 4 KB
  __shared__ float muL[MT], invL[MT];                  // 0.5 KB

#define bufB ((float*)asbuf)                       // [MT][SLOTP] conv combine slot

  const int tid = threadIdx.x;
  const int wv = tid >> 6, l = tid & 63, q = l >> 4, cl = l & 15;
  const int mgq = wv >> 3;                         // conv K-half
  const int ng = wv & 7;                           // conv col group (32 cols)
  const int rg = wv >> 3;                          // FFN row half (rows rg*32..)
  const int cg = wv & 7;                           // FFN col group (32 cols)
  const long tok0 = (long)blockIdx.x * MT;
  const int n0 = (int)(tok0 & (NNSEQ - 1));

  // ---- acc init + base pointers hoisted above staging ----
  f32x4 acc[4][2];
#pragma unroll
  for (int nt = 0; nt < 2; ++nt) {
    const float bm = (mgq == 0) ? bmix[ng * 32 + nt * 16 + cl] : 0.f;
#pragma unroll
    for (int mt = 0; mt < 4; ++mt) acc[mt][nt] = (f32x4){bm, bm, bm, bm};
  }
  const u16* bbase = wpk + (size_t)(mgq * 60) * 8192 + (size_t)(ng * 2) * 512 + (size_t)l * 8;

  // ---- stage x rows [tok0-14, tok0+63] as bf16 ----
  {
    const int cslot = l * 4;
    for (int r = wv; r < XR; r += 16) {
      const int nloc = n0 - 14 + r;
      float4 v = make_float4(0.f, 0.f, 0.f, 0.f);
      if (nloc >= 0) v = *(const float4*)&x[(tok0 - 14 + r) * DD + cslot];
      uint2 pk;
      pk.x = (unsigned)f2bf(v.x) | ((unsigned)f2bf(v.y) << 16);
      pk.y = (unsigned)f2bf(v.z) | ((unsigned)f2bf(v.w) << 16);
      *(uint2*)&bufA[r * XPITCH + cslot] = pk;
    }
  }

#define LOAD_A(dst, s_)                                                         \
  {                                                                             \
    const int ks = mgq * 60 + (s_);                                             \
    const int xrow = ks >> 3, c0 = (ks & 7) * 32;                               \
    _Pragma("unroll")                                                           \
    for (int mt = 0; mt < 4; ++mt)                                              \
      dst[mt] = *(const short8*)&bufA[(xrow + mt * 16 + cl) * XPITCH + c0 + q * 8]; \
  }
#define LOAD_B(dst, s_)                                                         \
  {                                                                             \
    const u16* bp = bbase + (size_t)(s_) * 8192;                                \
    _Pragma("unroll")                                                           \
    for (int nt = 0; nt < 2; ++nt)                                              \
      dst[nt] = *(const short8*)(bp + nt * 512);                                \
  }

  // ====== conv GEMM: K-half mgq, cols ng*32.., rows 0..63 (64x32) ========
  // Depth-2 pipeline; B (global) for steps 0..1 issued BEFORE the barrier.
  {
    short8 af[2][4], bfr[2][2];
    LOAD_B(bfr[0], 0)
    LOAD_B(bfr[1], 1)
    __syncthreads();
    LOAD_A(af[0], 0)
    LOAD_A(af[1], 1)

#pragma unroll 2
    for (int s = 0; s < 60; ++s) {
      const int cur = s & 1;
#pragma unroll
      for (int mt = 0; mt < 4; ++mt)
#pragma unroll
        for (int nt = 0; nt < 2; ++nt)
          acc[mt][nt] = MFMA(af[cur][mt], bfr[cur][nt], acc[mt][nt]);
      if (s + 2 < 60) {
        LOAD_A(af[cur], s + 2)
        LOAD_B(bfr[cur], s + 2)
      }
    }
  }
#undef LOAD_A
#undef LOAD_B

  // ---- mg1 -> fp32 slot; mg0 combines + residual + LN1 ----
  if (mgq == 1) {
#pragma unroll
    for (int mt = 0; mt < 4; ++mt)
#pragma unroll
      for (int nt = 0; nt < 2; ++nt)
#pragma unroll
        for (int reg = 0; reg < 4; ++reg)
          bufB[(mt * 16 + q * 4 + reg) * SLOTP + ng * 32 + nt * 16 + cl] = acc[mt][nt][reg];
  }
  __syncthreads();

  if (mgq == 0) {
    float ps[4][4], ps2[4][4];
#pragma unroll
    for (int mt = 0; mt < 4; ++mt)
#pragma unroll
      for (int reg = 0; reg < 4; ++reg) {
        const int row = mt * 16 + q * 4 + reg;
        float s = 0.f, s2 = 0.f;
#pragma unroll
        for (int nt = 0; nt < 2; ++nt) {
          const int col = ng * 32 + nt * 16 + cl;
          const float y = acc[mt][nt][reg] + bufB[row * SLOTP + col]
                        + x[(tok0 + row) * DD + col];        // fp32 residual
          acc[mt][nt][reg] = y;
          s += y; s2 += y * y;
        }
#pragma unroll
        for (int off = 1; off < 16; off <<= 1) { s += __shfl_xor(s, off, 64); s2 += __shfl_xor(s2, off, 64); }
        ps[mt][reg] = s; ps2[mt][reg] = s2;
      }
    if (cl == 0) {
#pragma unroll
      for (int mt = 0; mt < 4; ++mt)
#pragma unroll
        for (int reg = 0; reg < 4; ++reg) {
          const int row = mt * 16 + q * 4 + reg;
          redS[ng][row] = ps[mt][reg]; redS2[ng][row] = ps2[mt][reg];
        }
    }
  }
  __syncthreads();
  if (tid < MT) {
    float s = 0.f, s2 = 0.f;
#pragma unroll
    for (int k = 0; k < 8; ++k) { s += redS[k][tid]; s2 += redS2[k][tid]; }
    const float mu = s * (1.f / DD);
    const float var = s2 * (1.f / DD) - mu * mu;
    muL[tid] = mu; invL[tid] = rsqrtf(var + EPSLN);
  }
  __syncthreads();

  // ---- h (bf16) -> bufA rows 0..63 (mg0 waves, their 32 cols) ----
  if (mgq == 0) {
#pragma unroll
    for (int nt = 0; nt < 2; ++nt) {
      const int col = ng * 32 + nt * 16 + cl;
      const float gv = g1[col], bv = b1[col];
#pragma unroll
      for (int mt = 0; mt < 4; ++mt)
#pragma unroll
        for (int reg = 0; reg < 4; ++reg) {
          const int row = mt * 16 + q * 4 + reg;
          const float hv = (acc[mt][nt][reg] - muL[row]) * invL[row] * gv + bv;
          bufA[row * XPITCH + col] = f2bf(hv);
        }
    }
  }
  __syncthreads();

  // ============ FFN: 4 chunks of 256 H-cols; wave tile 32 x 32 ============
  // wave (rg, cg): rows rg*32.., cols cg*32.. of the chunk (R5 structure).
  // asb double-buffered by chunk parity: one barrier per chunk.
  f32x4 acc2[2][2];
#pragma unroll
  for (int nt = 0; nt < 2; ++nt) {
    const float bv = bf2[cg * 32 + nt * 16 + cl];
#pragma unroll
    for (int mt = 0; mt < 2; ++mt) acc2[mt][nt] = (f32x4){bv, bv, bv, bv};
  }

#define FF_LDA(src, dst, s_)                                                    \
  {                                                                             \
    _Pragma("unroll")                                                           \
    for (int mt = 0; mt < 2; ++mt)                                              \
      dst[mt] = *(const short8*)&src[(rg * 32 + mt * 16 + cl) * XPITCH + (s_) * 32 + q * 8]; \
  }
#define FF_LDB(wsrc, dst, s_)                                                   \
  {                                                                             \
    const u16* bp = wsrc + (size_t)(c * 8 + (s_)) * 8192 + (size_t)(cg * 2) * 512 + (size_t)l * 8; \
    _Pragma("unroll")                                                           \
    for (int nt = 0; nt < 2; ++nt)                                              \
      dst[nt] = *(const short8*)(bp + nt * 512);                                \
  }

  for (int c = 0; c < 4; ++c) {
    u16* asb = asbuf + (c & 1) * (MT * XPITCH);
    // FF1: rows rg*32.. x chunk-cols [cg*32,+32), K = 256
    f32x4 acc1[2][2];
#pragma unroll
    for (int nt = 0; nt < 2; ++nt) {
      const float bv = bf1[c * 256 + cg * 32 + nt * 16 + cl];
#pragma unroll
      for (int mt = 0; mt < 2; ++mt) acc1[mt][nt] = (f32x4){bv, bv, bv, bv};
    }
    {
      short8 a2[2][2], b2r[2][2];
      FF_LDA(bufA, a2[0], 0) FF_LDB(w1pk, b2r[0], 0)
      FF_LDA(bufA, a2[1], 1) FF_LDB(w1pk, b2r[1], 1)
#pragma unroll
      for (int s = 0; s < 6; ++s) {
        const int cur = s & 1;
#pragma unroll
        for (int mt = 0; mt < 2; ++mt)
#pragma unroll
          for (int nt = 0; nt < 2; ++nt)
            acc1[mt][nt] = MFMA(a2[cur][mt], b2r[cur][nt], acc1[mt][nt]);
        FF_LDA(bufA, a2[cur], s + 2) FF_LDB(w1pk, b2r[cur], s + 2)
      }
#pragma unroll
      for (int s = 6; s < 8; ++s) {
        const int cur = s & 1;
#pragma unroll
        for (int mt = 0; mt < 2; ++mt)
#pragma unroll
          for (int nt = 0; nt < 2; ++nt)
            acc1[mt][nt] = MFMA(a2[cur][mt], b2r[cur][nt], acc1[mt][nt]);
      }
    }
    // fast gelu -> asb (A-layout, chunk-local cols cg*32+nt*16+cl)
#pragma unroll
    for (int mt = 0; mt < 2; ++mt)
#pragma unroll
      for (int nt = 0; nt < 2; ++nt)
#pragma unroll
        for (int reg = 0; reg < 4; ++reg) {
          const float g = fast_gelu(acc1[mt][nt][reg]);
          asb[(rg * 32 + mt * 16 + q * 4 + reg) * XPITCH + cg * 32 + nt * 16 + cl] = f2bf(g);
        }
    __syncthreads();
    // FF2: rows rg*32.. x out-cols [cg*32,+32), K = chunk's 256
    {
      short8 a2[2][2], b2r[2][2];
      FF_LDA(asb, a2[0], 0) FF_LDB(w2pk, b2r[0], 0)
      FF_LDA(asb, a2[1], 1) FF_LDB(w2pk, b2r[1], 1)
#pragma unroll
      for (int s = 0; s < 6; ++s) {
        const int cur = s & 1;
#pragma unroll
        for (int mt = 0; mt < 2; ++mt)
#pragma unroll
          for (int nt = 0; nt < 2; ++nt)
            acc2[mt][nt] = MFMA(a2[cur][mt], b2r[cur][nt], acc2[mt][nt]);
        FF_LDA(asb, a2[cur], s + 2) FF_LDB(w2pk, b2r[cur], s + 2)
      }
#pragma unroll
      for (int s = 6; s < 8; ++s) {
        const int cur = s & 1;
#pragma unroll
        for (int mt = 0; mt < 2; ++mt)
#pragma unroll
          for (int nt = 0; nt < 2; ++nt)
            acc2[mt][nt] = MFMA(a2[cur][mt], b2r[cur][nt], acc2[mt][nt]);
      }
    }
    // no trailing barrier: next chunk writes the other asb buffer
  }
#undef FF_LDA
#undef FF_LDB

  // ---- residual (h from bufA) + LN2 ----
  {
    float ps[2][4], ps2[2][4];
#pragma unroll
    for (int mt = 0; mt < 2; ++mt)
#pragma unroll
      for (int reg = 0; reg < 4; ++reg) {
        const int row = rg * 32 + mt * 16 + q * 4 + reg;
        float s = 0.f, s2 = 0.f;
#pragma unroll
        for (int nt = 0; nt < 2; ++nt) {
          const int col = cg * 32 + nt * 16 + cl;
          const float y = acc2[mt][nt][reg] + bf2f(bufA[row * XPITCH + col]);
          acc2[mt][nt][reg] = y;
          s += y; s2 += y * y;
        }
#pragma unroll
        for (int off = 1; off < 16; off <<= 1) { s += __shfl_xor(s, off, 64); s2 += __shfl_xor(s2, off, 64); }
        ps[mt][reg] = s; ps2[mt][reg] = s2;
      }
    if (cl == 0) {
#pragma unroll
      for (int mt = 0; mt < 2; ++mt)
#pragma unroll
        for (int reg = 0; reg < 4; ++reg) {
          const int row = rg * 32 + mt * 16 + q * 4 + reg;
          redS[cg][row] = ps[mt][reg]; redS2[cg][row] = ps2[mt][reg];
        }
    }
  }
  __syncthreads();
  if (tid < MT) {
    float s = 0.f, s2 = 0.f;
#pragma unroll
    for (int k = 0; k < 8; ++k) { s += redS[k][tid]; s2 += redS2[k][tid]; }
    const float mu = s * (1.f / DD);
    const float var = s2 * (1.f / DD) - mu * mu;
    muL[tid] = mu; invL[tid] = rsqrtf(var + EPSLN);
  }
  __syncthreads();

#pragma unroll
  for (int nt = 0; nt < 2; ++nt) {
    const int col = cg * 32 + nt * 16 + cl;
    const float gv = g2[col], bv = b2[col];
#pragma unroll
    for (int mt = 0; mt < 2; ++mt)
#pragma unroll
      for (int reg = 0; reg < 4; ++reg) {
        const int row = rg * 32 + mt * 16 + q * 4 + reg;
        out[(tok0 + row) * DD + col] = (acc2[mt][nt][reg] - muL[row]) * invL[row] * gv + bv;
      }
  }
#undef bufB
}

// ---------------- launch ----------------
extern "C" void kernel_launch(void* const* d_in, const int* in_sizes, int n_in,
                              void* d_out, int out_size, void* d_ws, size_t ws_size,
                              hipStream_t stream) {
  const float* x    = (const float*)d_in[0];
  const float* wmix = (const float*)d_in[1];   // [3840][256]
  const float* bmix = (const float*)d_in[2];
  const float* g1   = (const float*)d_in[3];
  const float* b1   = (const float*)d_in[4];
  const float* wff1 = (const float*)d_in[5];   // [256][1024]
  const float* bff1 = (const float*)d_in[6];
  const float* wff2 = (const float*)d_in[7];   // [1024][256]
  const float* bff2 = (const float*)d_in[8];
  const float* g2   = (const float*)d_in[9];
  const float* b2   = (const float*)d_in[10];
  float* out = (float*)d_out;

  u16* wpk  = (u16*)d_ws;                // 120*8192 = 983040 elems (1.97 MB)
  u16* w1pk = wpk + 983040;              // 32*8192 = 262144
  u16* w2pk = w1pk + 262144;             // 262144

  k_prep<<<184, 256, 0, stream>>>(wmix, wff1, wff2, wpk, w1pk, w2pk);

  k_fused<<<256, 1024, 0, stream>>>(x, wpk, bmix, g1, b1,
                                    w1pk, bff1, w2pk, bff2, g2, b2, out);
}